// Round 1
// baseline (918.467 us; speedup 1.0000x reference)
//
#include <hip/hip_runtime.h>
#include <math.h>

// Problem constants (fixed by setup_inputs): B=2, C=19, H=W=512, fp32 everywhere.
constexpr int H = 512, W = 512, B = 2;
constexpr int HW = H * W;

// ---------------------------------------------------------------------------
// Tiled 3x3 conv, pad=1, NCHW. Input may be a channel-concat of two tensors
// (in0 with CIN0 channels, in1 with CIN1). Each block computes a 16x16 pixel
// tile for ALL COUT channels; input tile (with halo) staged in LDS; weights
// read via uniform (scalar) loads.
// ---------------------------------------------------------------------------
template <int CIN0, int CIN1, int COUT, bool RELU>
__global__ __launch_bounds__(256) void conv3x3_kernel(
    const float* __restrict__ in0, const float* __restrict__ in1,
    const float* __restrict__ wgt, const float* __restrict__ bias,
    float* __restrict__ out) {
  constexpr int CIN = CIN0 + CIN1;
  constexpr int TS = 16, TH = 18, LDW = 20;  // tile, halo'd tile, LDS stride
  __shared__ float tile[CIN][TH][LDW];

  const int tx = threadIdx.x, ty = threadIdx.y;
  const int tid = ty * 16 + tx;
  const int w0 = blockIdx.x * TS, h0 = blockIdx.y * TS, b = blockIdx.z;

  // Stage halo'd input tile (zero pad at image borders).
  for (int idx = tid; idx < CIN * TH * TH; idx += 256) {
    const int cin = idx / (TH * TH);
    const int rem = idx - cin * (TH * TH);
    const int r = rem / TH, c = rem - r * TH;
    const int gh = h0 + r - 1, gw = w0 + c - 1;
    float v = 0.f;
    if ((unsigned)gh < (unsigned)H && (unsigned)gw < (unsigned)W) {
      if (CIN1 == 0 || cin < CIN0)
        v = in0[(size_t)(b * CIN0 + cin) * HW + gh * W + gw];
      else
        v = in1[(size_t)(b * CIN1 + (cin - CIN0)) * HW + gh * W + gw];
    }
    tile[cin][r][c] = v;
  }
  __syncthreads();

  float acc[COUT];
#pragma unroll
  for (int co = 0; co < COUT; ++co) acc[co] = bias[co];

  for (int cin = 0; cin < CIN; ++cin) {
#pragma unroll
    for (int t = 0; t < 9; ++t) {
      const int ky = t / 3, kx = t - ky * 3;
      const float v = tile[cin][ty + ky][tx + kx];
#pragma unroll
      for (int co = 0; co < COUT; ++co)
        acc[co] = fmaf(v, wgt[(co * CIN + cin) * 9 + t], acc[co]);
    }
  }

  const int oh = h0 + ty, ow = w0 + tx;
#pragma unroll
  for (int co = 0; co < COUT; ++co) {
    float v = acc[co];
    if (RELU) v = fmaxf(v, 0.f);
    out[(size_t)(b * COUT + co) * HW + oh * W + ow] = v;
  }
}

// ---------------------------------------------------------------------------
// argmax over 19 channels -> float index (first max wins, matching jnp.argmax)
// ---------------------------------------------------------------------------
__global__ __launch_bounds__(256) void argmax_kernel(
    const float* __restrict__ x, float* __restrict__ sx) {
  const int p = blockIdx.x * 256 + threadIdx.x;
  if (p >= B * HW) return;
  const int b = p / HW, s = p - b * HW;
  const float* xp = x + (size_t)b * 19 * HW + s;
  float best = xp[0];
  int bi = 0;
#pragma unroll
  for (int c = 1; c < 19; ++c) {
    const float v = xp[(size_t)c * HW];
    if (v > best) { best = v; bi = c; }
  }
  sx[p] = (float)bi;
}

// Laplacian (all-ones, center -8), pad=1, on the argmax map.
__global__ __launch_bounds__(256) void edge_kernel(
    const float* __restrict__ sx, float* __restrict__ edge) {
  const int p = blockIdx.x * 256 + threadIdx.x;
  if (p >= B * HW) return;
  const int b = p / HW, s = p - b * HW;
  const int h = s / W, w = s - h * W;
  const float* sp = sx + (size_t)b * HW;
  const float cv = sp[s];
  float sum = 0.f;
#pragma unroll
  for (int dy = -1; dy <= 1; ++dy)
#pragma unroll
    for (int dx = -1; dx <= 1; ++dx) {
      if (dy == 0 && dx == 0) continue;
      const int hh = h + dy, ww = w + dx;
      if ((unsigned)hh < (unsigned)H && (unsigned)ww < (unsigned)W)
        sum += sp[hh * W + ww];
    }
  edge[p] = sum - 8.f * cv;
}

// 1x1 conv 16 -> 19 (intra head), no activation.
__global__ __launch_bounds__(256) void conv1x1_16_19(
    const float* __restrict__ in, const float* __restrict__ wgt,
    const float* __restrict__ bias, float* __restrict__ out) {
  const int p = blockIdx.x * 256 + threadIdx.x;
  if (p >= B * HW) return;
  const int b = p / HW, s = p - b * HW;
  float xi[16];
#pragma unroll
  for (int c = 0; c < 16; ++c) xi[c] = in[(size_t)(b * 16 + c) * HW + s];
#pragma unroll
  for (int co = 0; co < 19; ++co) {
    float a = bias[co];
#pragma unroll
    for (int c = 0; c < 16; ++c) a = fmaf(xi[c], wgt[co * 16 + c], a);
    out[(size_t)(b * 19 + co) * HW + s] = a;
  }
}

// 1x1 conv 32 -> 11 + sigmoid + normalize across the 11 channels -> guide_feat
__global__ __launch_bounds__(256) void guide3_kernel(
    const float* __restrict__ in, const float* __restrict__ wgt,
    const float* __restrict__ bias, float* __restrict__ gf) {
  const int p = blockIdx.x * 256 + threadIdx.x;
  if (p >= B * HW) return;
  const int b = p / HW, s = p - b * HW;
  float xi[32];
#pragma unroll
  for (int c = 0; c < 32; ++c) xi[c] = in[(size_t)(b * 32 + c) * HW + s];
  float g[11];
  float sum = 0.f;
#pragma unroll
  for (int co = 0; co < 11; ++co) {
    float a = bias[co];
#pragma unroll
    for (int c = 0; c < 32; ++c) a = fmaf(xi[c], wgt[co * 32 + c], a);
    const float gg = 1.f / (1.f + expf(-a));
    g[co] = gg;
    sum += gg;
  }
  const float inv = 1.f / (sum + 1e-9f);
#pragma unroll
  for (int co = 0; co < 11; ++co)
    gf[(size_t)(b * 11 + co) * HW + s] = g[co] * inv;
}

// out[b,c,h,w] = gf0*x + sum_{m=1..8} gf_m * x(shifted) + gf10*intra
// (gf9 multiplies the all-zero 9th shift channel -> skipped)
__global__ __launch_bounds__(256) void combine_kernel(
    const float* __restrict__ x, const float* __restrict__ intra,
    const float* __restrict__ gf, float* __restrict__ out) {
  const int idx = blockIdx.x * 256 + threadIdx.x;
  if (idx >= B * 19 * HW) return;
  const int b = idx / (19 * HW);
  const int rem = idx - b * 19 * HW;
  const int c = rem / HW;
  const int s = rem - c * HW;
  const int h = s / W, w = s - h * W;
  const float* gp = gf + (size_t)b * 11 * HW + s;
  const float* xc = x + (size_t)(b * 19 + c) * HW;

  float acc = gp[0] * xc[s];
  const int dy[8] = {-1, -1, -1, 0, 0, 1, 1, 1};
  const int dx[8] = {-1, 0, 1, -1, 1, -1, 0, 1};
#pragma unroll
  for (int m = 0; m < 8; ++m) {
    const int hh = h + dy[m], ww = w + dx[m];
    if ((unsigned)hh < (unsigned)H && (unsigned)ww < (unsigned)W)
      acc = fmaf(gp[(size_t)(m + 1) * HW], xc[hh * W + ww], acc);
  }
  acc = fmaf(gp[(size_t)10 * HW], intra[(size_t)(b * 19 + c) * HW + s], acc);
  out[idx] = acc;
}

// ---------------------------------------------------------------------------
extern "C" void kernel_launch(void* const* d_in, const int* in_sizes, int n_in,
                              void* d_out, int out_size, void* d_ws,
                              size_t ws_size, hipStream_t stream) {
  const float* x     = (const float*)d_in[0];
  const float* image = (const float*)d_in[1];
  const float* iw1 = (const float*)d_in[2];
  const float* ib1 = (const float*)d_in[3];
  const float* iw2 = (const float*)d_in[4];
  const float* ib2 = (const float*)d_in[5];
  const float* iw3 = (const float*)d_in[6];
  const float* ib3 = (const float*)d_in[7];
  const float* gw1 = (const float*)d_in[8];
  const float* gb1 = (const float*)d_in[9];
  const float* gw2 = (const float*)d_in[10];
  const float* gb2 = (const float*)d_in[11];
  const float* gw3 = (const float*)d_in[12];
  const float* gb3 = (const float*)d_in[13];

  float* ws = (float*)d_ws;
  // Workspace layout (floats). g1 reuses the dead f1+f2 region (exact fit).
  float* f1    = ws;                              // 2*16*HW
  float* f2    = ws + (size_t)2 * 16 * HW;        // 2*16*HW
  float* intra = ws + (size_t)4 * 16 * HW;        // 2*19*HW
  float* sx    = intra + (size_t)2 * 19 * HW;     // 2*HW
  float* g1    = ws;                              // 2*32*HW (over f1,f2)
  float* g2    = sx + (size_t)2 * HW;             // 2*32*HW
  // total: 168*HW floats = 176 MB

  float* out0 = (float*)d_out;                 // (2,19,512,512)
  float* gfo  = out0 + (size_t)2 * 19 * HW;    // (2,11,1,512,512)
  float* edg  = gfo + (size_t)2 * 11 * HW;     // (2,1,512,512)

  const dim3 blk(16, 16);
  const dim3 grd(W / 16, H / 16, B);
  const int flat = (B * HW) / 256;  // 2048

  conv3x3_kernel<3, 0, 16, true><<<grd, blk, 0, stream>>>(image, nullptr, iw1, ib1, f1);
  conv3x3_kernel<16, 0, 16, true><<<grd, blk, 0, stream>>>(f1, nullptr, iw2, ib2, f2);
  conv1x1_16_19<<<flat, 256, 0, stream>>>(f2, iw3, ib3, intra);
  argmax_kernel<<<flat, 256, 0, stream>>>(x, sx);
  edge_kernel<<<flat, 256, 0, stream>>>(sx, edg);
  conv3x3_kernel<19, 1, 32, true><<<grd, blk, 0, stream>>>(intra, edg, gw1, gb1, g1);
  conv3x3_kernel<32, 0, 32, true><<<grd, blk, 0, stream>>>(g1, nullptr, gw2, gb2, g2);
  guide3_kernel<<<flat, 256, 0, stream>>>(g2, gw3, gb3, gfo);
  combine_kernel<<<(B * 19 * HW) / 256, 256, 0, stream>>>(x, intra, gfo, out0);
}

// Round 2
// 377.329 us; speedup vs baseline: 2.4341x; 2.4341x over previous
//
#include <hip/hip_runtime.h>
#include <math.h>

// Problem constants (fixed by setup_inputs): B=2, C=19, H=W=512, fp32 in/out.
constexpr int H = 512, W = 512, B = 2;
constexpr int HW = H * W;

typedef __attribute__((ext_vector_type(8))) short short8;
typedef __attribute__((ext_vector_type(4))) float floatx4;

__device__ inline unsigned short f2bf(float f) {
  union { float f; unsigned int u; } x{f};
  const unsigned int u = x.u;
  return (unsigned short)((u + 0x7FFFu + ((u >> 16) & 1u)) >> 16);
}

// ---------------------------------------------------------------------------
// fp32 tiled 3x3 conv (kept only for intra conv1: 3->16, tiny work).
// ---------------------------------------------------------------------------
template <int CIN, int COUT, bool RELU>
__global__ __launch_bounds__(256) void conv3x3_fp32(
    const float* __restrict__ in0, const float* __restrict__ wgt,
    const float* __restrict__ bias, float* __restrict__ out) {
  constexpr int TS = 16, TH = 18, LDW = 20;
  __shared__ float tile[CIN][TH][LDW];
  const int tx = threadIdx.x, ty = threadIdx.y;
  const int tid = ty * 16 + tx;
  const int w0 = blockIdx.x * TS, h0 = blockIdx.y * TS, b = blockIdx.z;

  for (int idx = tid; idx < CIN * TH * TH; idx += 256) {
    const int cin = idx / (TH * TH);
    const int rem = idx - cin * (TH * TH);
    const int r = rem / TH, c = rem - r * TH;
    const int gh = h0 + r - 1, gw = w0 + c - 1;
    float v = 0.f;
    if ((unsigned)gh < (unsigned)H && (unsigned)gw < (unsigned)W)
      v = in0[(size_t)(b * CIN + cin) * HW + gh * W + gw];
    tile[cin][r][c] = v;
  }
  __syncthreads();

  float acc[COUT];
#pragma unroll
  for (int co = 0; co < COUT; ++co) acc[co] = bias[co];
  for (int cin = 0; cin < CIN; ++cin) {
#pragma unroll
    for (int t = 0; t < 9; ++t) {
      const int ky = t / 3, kx = t - ky * 3;
      const float v = tile[cin][ty + ky][tx + kx];
#pragma unroll
      for (int co = 0; co < COUT; ++co)
        acc[co] = fmaf(v, wgt[(co * CIN + cin) * 9 + t], acc[co]);
    }
  }
  const int oh = h0 + ty, ow = w0 + tx;
#pragma unroll
  for (int co = 0; co < COUT; ++co) {
    float v = acc[co];
    if (RELU) v = fmaxf(v, 0.f);
    out[(size_t)(b * COUT + co) * HW + oh * W + ow] = v;
  }
}

// ---------------------------------------------------------------------------
// Weight repack into B-fragment order for mfma_f32_16x16x32_bf16.
// Bpack[((nt*KS + ks)*64 + lane)*8 + j] = W[co=nt*16+(lane&15)]
//          [k = ks*32 + (lane>>4)*8 + j]  with k -> (tap = k/CINP, cin = k%CINP)
// Zero-padded for cin >= CIN or tap >= 9.
// ---------------------------------------------------------------------------
template <int CIN, int CINP, int COUT, int KS>
__global__ __launch_bounds__(256) void repack_w(
    const float* __restrict__ w, unsigned short* __restrict__ bp) {
  constexpr int NT = COUT / 16;
  const int idx = blockIdx.x * 256 + threadIdx.x;
  if (idx >= NT * KS * 512) return;
  const int j = idx & 7;
  const int l = (idx >> 3) & 63;
  const int ks = (idx >> 9) % KS;
  const int nt = idx / (KS * 512);
  const int co = nt * 16 + (l & 15);
  const int kglob = ks * 32 + (l >> 4) * 8 + j;
  const int tap = kglob / CINP;  // CINP is pow2
  const int cin = kglob & (CINP - 1);
  float v = 0.f;
  if (tap < 9 && cin < CIN) v = w[((size_t)co * CIN + cin) * 9 + tap];
  bp[idx] = f2bf(v);
}

// ---------------------------------------------------------------------------
// Implicit-GEMM 3x3 conv via bf16 MFMA, fp32 accumulate.
// Tile: 16 rows x 32 cols per block (256 thr = 4 waves, each wave 4 rows).
// LDS: channels-last bf16 tile [18][34][CINP+8].
// ---------------------------------------------------------------------------
template <int CIN0, int CIN1, int CINP, int COUT, bool RELU>
__global__ __launch_bounds__(256) void conv3x3_mfma(
    const float* __restrict__ in0, const float* __restrict__ in1,
    const unsigned short* __restrict__ bpack, const float* __restrict__ bias,
    float* __restrict__ out) {
  constexpr int CIN = CIN0 + CIN1;
  constexpr int NT = COUT / 16;
  constexpr int KS = (CINP == 32) ? 9 : 5;   // K-steps of 32
  constexpr int CS = CINP + 8;               // cin stride (bf16 elems)
  constexpr int TILE_BYTES = 18 * 34 * CS * 2;
  constexpr int EPI_BYTES = 4 * (16 * 4 * 33) * 4;  // 4 waves x 2112 floats
  constexpr int SMEM = (TILE_BYTES > EPI_BYTES) ? TILE_BYTES : EPI_BYTES;
  __shared__ __align__(16) char smem[SMEM];
  unsigned short* tile = (unsigned short*)smem;

  const int tid = threadIdx.x;
  const int w0 = blockIdx.x * 32, h0 = blockIdx.y * 16, b = blockIdx.z;

  // ---- stage halo'd tile, channels-last, fp32 -> bf16, 2 cins per store ----
  {
    constexpr int PAIRS = CINP / 2;
    constexpr int TOTAL = 18 * 34 * PAIRS;
    for (int idx = tid; idx < TOTAL; idx += 256) {
      const int cp = idx / (18 * 34);
      const int rc = idx - cp * (18 * 34);
      const int r = rc / 34, c = rc - r * 34;
      const int gh = h0 + r - 1, gw = w0 + c - 1;
      const int c0 = cp * 2;
      float v0 = 0.f, v1 = 0.f;
      if ((unsigned)gh < (unsigned)H && (unsigned)gw < (unsigned)W) {
        const size_t sp = (size_t)gh * W + gw;
        if (c0 < CIN0) v0 = in0[(size_t)(b * CIN0 + c0) * HW + sp];
        else if (c0 < CIN) v0 = in1[(size_t)(b * CIN1 + (c0 - CIN0)) * HW + sp];
        const int c1 = c0 + 1;
        if (c1 < CIN0) v1 = in0[(size_t)(b * CIN0 + c1) * HW + sp];
        else if (c1 < CIN) v1 = in1[(size_t)(b * CIN1 + (c1 - CIN0)) * HW + sp];
      }
      union { unsigned int u; unsigned short s[2]; } pk;
      pk.s[0] = f2bf(v0);
      pk.s[1] = f2bf(v1);
      *(unsigned int*)&tile[(size_t)(r * 34 + c) * CS + c0] = pk.u;
    }
  }
  __syncthreads();

  // ---- K-loop ----
  const int wv = tid >> 6, lane = tid & 63;
  const int q = lane >> 4, l15 = lane & 15;
  const int rb = wv * 4;  // wave's first output row in tile

  floatx4 acc[8][NT];
#pragma unroll
  for (int mf = 0; mf < 8; ++mf)
#pragma unroll
    for (int nt = 0; nt < NT; ++nt) acc[mf][nt] = floatx4{0.f, 0.f, 0.f, 0.f};

  for (int ks = 0; ks < KS; ++ks) {
    short8 bfrag[NT];
#pragma unroll
    for (int nt = 0; nt < NT; ++nt)
      bfrag[nt] = *(const short8*)(bpack + (size_t)(((nt * KS) + ks) * 64 + lane) * 8);

    int tap, cin0l;
    if (CINP == 32) { tap = ks; cin0l = q * 8; }
    else { tap = ks * 2 + (q >> 1); cin0l = (q & 1) * 8; if (tap > 8) tap = 8; }
    const int ky = tap / 3, kx = tap - ky * 3;
    const int baseE = ((rb + ky) * 34 + (l15 + kx)) * CS + cin0l;
    const char* aptr = smem + (size_t)baseE * 2;

#pragma unroll
    for (int mf = 0; mf < 8; ++mf) {
      constexpr int mfs[8][2] = {{0,0},{0,16},{1,0},{1,16},{2,0},{2,16},{3,0},{3,16}};
      const int off = (mfs[mf][0] * 34 + mfs[mf][1]) * CS * 2;
      const short8 af = *(const short8*)(aptr + off);
#pragma unroll
      for (int nt = 0; nt < NT; ++nt)
        acc[mf][nt] = __builtin_amdgcn_mfma_f32_16x16x32_bf16(
            af, bfrag[nt], acc[mf][nt], 0, 0, 0);
    }
  }

  __syncthreads();  // done reading tile; epilogue reuses smem

  // ---- epilogue: LDS transpose per wave, coalesced stores ----
  float* ep = (float*)smem + wv * 2112;  // 16co x 4r x (32+1)
  const int row_i = lane >> 5, colr = lane & 31;
#pragma unroll
  for (int nt = 0; nt < NT; ++nt) {
    if (nt) __syncthreads();
    const float bv = bias[nt * 16 + l15];
#pragma unroll
    for (int mf = 0; mf < 8; ++mf) {
      const int r = mf >> 1;
      const int colbase = (mf & 1) * 16 + q * 4;
#pragma unroll
      for (int rg = 0; rg < 4; ++rg) {
        float v = acc[mf][nt][rg] + bv;  // D: n=l15(co), m=q*4+rg (pixel col)
        if (RELU) v = fmaxf(v, 0.f);
        ep[(l15 * 4 + r) * 33 + colbase + rg] = v;
      }
    }
    const int cog = nt * 16;
#pragma unroll
    for (int jj = 0; jj < 32; ++jj) {
      const int cr = jj * 2 + row_i;
      const int co = cr >> 2, r = cr & 3;
      const float v = ep[cr * 33 + colr];
      out[((size_t)(b * COUT + cog + co)) * HW + (size_t)(h0 + rb + r) * W + w0 + colr] = v;
    }
  }
}

// ---------------------------------------------------------------------------
// argmax over 19 channels -> float index (first max wins)
// ---------------------------------------------------------------------------
__global__ __launch_bounds__(256) void argmax_kernel(
    const float* __restrict__ x, float* __restrict__ sx) {
  const int p = blockIdx.x * 256 + threadIdx.x;
  if (p >= B * HW) return;
  const int b = p / HW, s = p - b * HW;
  const float* xp = x + (size_t)b * 19 * HW + s;
  float best = xp[0];
  int bi = 0;
#pragma unroll
  for (int c = 1; c < 19; ++c) {
    const float v = xp[(size_t)c * HW];
    if (v > best) { best = v; bi = c; }
  }
  sx[p] = (float)bi;
}

__global__ __launch_bounds__(256) void edge_kernel(
    const float* __restrict__ sx, float* __restrict__ edge) {
  const int p = blockIdx.x * 256 + threadIdx.x;
  if (p >= B * HW) return;
  const int b = p / HW, s = p - b * HW;
  const int h = s / W, w = s - h * W;
  const float* sp = sx + (size_t)b * HW;
  const float cv = sp[s];
  float sum = 0.f;
#pragma unroll
  for (int dy = -1; dy <= 1; ++dy)
#pragma unroll
    for (int dx = -1; dx <= 1; ++dx) {
      if (dy == 0 && dx == 0) continue;
      const int hh = h + dy, ww = w + dx;
      if ((unsigned)hh < (unsigned)H && (unsigned)ww < (unsigned)W)
        sum += sp[hh * W + ww];
    }
  edge[p] = sum - 8.f * cv;
}

__global__ __launch_bounds__(256) void conv1x1_16_19(
    const float* __restrict__ in, const float* __restrict__ wgt,
    const float* __restrict__ bias, float* __restrict__ out) {
  const int p = blockIdx.x * 256 + threadIdx.x;
  if (p >= B * HW) return;
  const int b = p / HW, s = p - b * HW;
  float xi[16];
#pragma unroll
  for (int c = 0; c < 16; ++c) xi[c] = in[(size_t)(b * 16 + c) * HW + s];
#pragma unroll
  for (int co = 0; co < 19; ++co) {
    float a = bias[co];
#pragma unroll
    for (int c = 0; c < 16; ++c) a = fmaf(xi[c], wgt[co * 16 + c], a);
    out[(size_t)(b * 19 + co) * HW + s] = a;
  }
}

__global__ __launch_bounds__(256) void guide3_kernel(
    const float* __restrict__ in, const float* __restrict__ wgt,
    const float* __restrict__ bias, float* __restrict__ gf) {
  const int p = blockIdx.x * 256 + threadIdx.x;
  if (p >= B * HW) return;
  const int b = p / HW, s = p - b * HW;
  float xi[32];
#pragma unroll
  for (int c = 0; c < 32; ++c) xi[c] = in[(size_t)(b * 32 + c) * HW + s];
  float g[11];
  float sum = 0.f;
#pragma unroll
  for (int co = 0; co < 11; ++co) {
    float a = bias[co];
#pragma unroll
    for (int c = 0; c < 32; ++c) a = fmaf(xi[c], wgt[co * 32 + c], a);
    const float gg = 1.f / (1.f + expf(-a));
    g[co] = gg;
    sum += gg;
  }
  const float inv = 1.f / (sum + 1e-9f);
#pragma unroll
  for (int co = 0; co < 11; ++co)
    gf[(size_t)(b * 11 + co) * HW + s] = g[co] * inv;
}

__global__ __launch_bounds__(256) void combine_kernel(
    const float* __restrict__ x, const float* __restrict__ intra,
    const float* __restrict__ gf, float* __restrict__ out) {
  const int idx = blockIdx.x * 256 + threadIdx.x;
  if (idx >= B * 19 * HW) return;
  const int b = idx / (19 * HW);
  const int rem = idx - b * 19 * HW;
  const int c = rem / HW;
  const int s = rem - c * HW;
  const int h = s / W, w = s - h * W;
  const float* gp = gf + (size_t)b * 11 * HW + s;
  const float* xc = x + (size_t)(b * 19 + c) * HW;

  float acc = gp[0] * xc[s];
  const int dy[8] = {-1, -1, -1, 0, 0, 1, 1, 1};
  const int dx[8] = {-1, 0, 1, -1, 1, -1, 0, 1};
#pragma unroll
  for (int m = 0; m < 8; ++m) {
    const int hh = h + dy[m], ww = w + dx[m];
    if ((unsigned)hh < (unsigned)H && (unsigned)ww < (unsigned)W)
      acc = fmaf(gp[(size_t)(m + 1) * HW], xc[hh * W + ww], acc);
  }
  acc = fmaf(gp[(size_t)10 * HW], intra[(size_t)(b * 19 + c) * HW + s], acc);
  out[idx] = acc;
}

// ---------------------------------------------------------------------------
extern "C" void kernel_launch(void* const* d_in, const int* in_sizes, int n_in,
                              void* d_out, int out_size, void* d_ws,
                              size_t ws_size, hipStream_t stream) {
  const float* x     = (const float*)d_in[0];
  const float* image = (const float*)d_in[1];
  const float* iw1 = (const float*)d_in[2];
  const float* ib1 = (const float*)d_in[3];
  const float* iw2 = (const float*)d_in[4];
  const float* ib2 = (const float*)d_in[5];
  const float* iw3 = (const float*)d_in[6];
  const float* ib3 = (const float*)d_in[7];
  const float* gw1 = (const float*)d_in[8];
  const float* gb1 = (const float*)d_in[9];
  const float* gw2 = (const float*)d_in[10];
  const float* gb2 = (const float*)d_in[11];
  const float* gw3 = (const float*)d_in[12];
  const float* gb3 = (const float*)d_in[13];

  float* ws = (float*)d_ws;
  // Workspace layout (floats); g1 reuses f1+f2 (exact 64*HW fit).
  float* f1    = ws;                           // 2*16*HW
  float* f2    = ws + (size_t)2 * 16 * HW;     // 2*16*HW
  float* intra = ws + (size_t)4 * 16 * HW;     // 2*19*HW
  float* sx    = intra + (size_t)2 * 19 * HW;  // 2*HW (argmax map, then Bpacks)
  float* g1    = ws;                           // 2*32*HW
  float* g2    = sx + (size_t)2 * HW;          // 2*32*HW   (total 168*HW floats)

  // Bpack buffers live in the sx region AFTER edge_kernel consumed sx.
  unsigned short* bp_ic2 = (unsigned short*)sx;          // 2560 elems
  unsigned short* bp_gc1 = (unsigned short*)sx + 4096;   // 9216 elems
  unsigned short* bp_gc2 = (unsigned short*)sx + 16384;  // 9216 elems

  float* out0 = (float*)d_out;               // (2,19,512,512)
  float* gfo  = out0 + (size_t)2 * 19 * HW;  // (2,11,1,512,512)
  float* edg  = gfo + (size_t)2 * 11 * HW;   // (2,1,512,512)

  const dim3 blk16(16, 16);
  const dim3 grd16(W / 16, H / 16, B);
  const dim3 blkM(256);
  const dim3 grdM(W / 32, H / 16, B);
  const int flat = (B * HW) / 256;  // 2048

  // argmax/edge first so the sx region is free for Bpacks afterwards.
  argmax_kernel<<<flat, 256, 0, stream>>>(x, sx);
  edge_kernel<<<flat, 256, 0, stream>>>(sx, edg);

  repack_w<16, 16, 16, 5><<<10, 256, 0, stream>>>(iw2, bp_ic2);
  repack_w<20, 32, 32, 9><<<36, 256, 0, stream>>>(gw1, bp_gc1);
  repack_w<32, 32, 32, 9><<<36, 256, 0, stream>>>(gw2, bp_gc2);

  conv3x3_fp32<3, 16, true><<<grd16, blk16, 0, stream>>>(image, iw1, ib1, f1);
  conv3x3_mfma<16, 0, 16, 16, true><<<grdM, blkM, 0, stream>>>(f1, nullptr, bp_ic2, ib2, f2);
  conv1x1_16_19<<<flat, 256, 0, stream>>>(f2, iw3, ib3, intra);
  conv3x3_mfma<19, 1, 32, 32, true><<<grdM, blkM, 0, stream>>>(intra, edg, bp_gc1, gb1, g1);
  conv3x3_mfma<32, 0, 32, 32, true><<<grdM, blkM, 0, stream>>>(g1, nullptr, bp_gc2, gb2, g2);
  guide3_kernel<<<flat, 256, 0, stream>>>(g2, gw3, gb3, gfo);
  combine_kernel<<<(B * 19 * HW) / 256, 256, 0, stream>>>(x, intra, gfo, out0);
}

// Round 3
// 330.276 us; speedup vs baseline: 2.7809x; 1.1425x over previous
//
#include <hip/hip_runtime.h>
#include <math.h>

// Problem constants (fixed by setup_inputs): B=2, C=19, H=W=512, fp32 in/out.
constexpr int H = 512, W = 512, B = 2;
constexpr int HW = H * W;

typedef __attribute__((ext_vector_type(8))) short short8;
typedef __attribute__((ext_vector_type(4))) float floatx4;

__device__ inline unsigned short f2bf(float f) {
  union { float f; unsigned int u; } x{f};
  const unsigned int u = x.u;
  return (unsigned short)((u + 0x7FFFu + ((u >> 16) & 1u)) >> 16);
}

// ---------------------------------------------------------------------------
// fp32 tiled 3x3 conv (kept only for intra conv1: 3->16, tiny work).
// ---------------------------------------------------------------------------
template <int CIN, int COUT, bool RELU>
__global__ __launch_bounds__(256) void conv3x3_fp32(
    const float* __restrict__ in0, const float* __restrict__ wgt,
    const float* __restrict__ bias, float* __restrict__ out) {
  constexpr int TS = 16, TH = 18, LDW = 20;
  __shared__ float tile[CIN][TH][LDW];
  const int tx = threadIdx.x, ty = threadIdx.y;
  const int tid = ty * 16 + tx;
  const int w0 = blockIdx.x * TS, h0 = blockIdx.y * TS, b = blockIdx.z;

  for (int idx = tid; idx < CIN * TH * TH; idx += 256) {
    const int cin = idx / (TH * TH);
    const int rem = idx - cin * (TH * TH);
    const int r = rem / TH, c = rem - r * TH;
    const int gh = h0 + r - 1, gw = w0 + c - 1;
    float v = 0.f;
    if ((unsigned)gh < (unsigned)H && (unsigned)gw < (unsigned)W)
      v = in0[(size_t)(b * CIN + cin) * HW + gh * W + gw];
    tile[cin][r][c] = v;
  }
  __syncthreads();

  float acc[COUT];
#pragma unroll
  for (int co = 0; co < COUT; ++co) acc[co] = bias[co];
  for (int cin = 0; cin < CIN; ++cin) {
#pragma unroll
    for (int t = 0; t < 9; ++t) {
      const int ky = t / 3, kx = t - ky * 3;
      const float v = tile[cin][ty + ky][tx + kx];
#pragma unroll
      for (int co = 0; co < COUT; ++co)
        acc[co] = fmaf(v, wgt[(co * CIN + cin) * 9 + t], acc[co]);
    }
  }
  const int oh = h0 + ty, ow = w0 + tx;
#pragma unroll
  for (int co = 0; co < COUT; ++co) {
    float v = acc[co];
    if (RELU) v = fmaxf(v, 0.f);
    out[(size_t)(b * COUT + co) * HW + oh * W + ow] = v;
  }
}

// ---------------------------------------------------------------------------
// Weight repack into B-fragment order for mfma_f32_16x16x32_bf16.
// ---------------------------------------------------------------------------
template <int CIN, int CINP, int COUT, int KS>
__global__ __launch_bounds__(256) void repack_w(
    const float* __restrict__ w, unsigned short* __restrict__ bp) {
  constexpr int NT = COUT / 16;
  const int idx = blockIdx.x * 256 + threadIdx.x;
  if (idx >= NT * KS * 512) return;
  const int j = idx & 7;
  const int l = (idx >> 3) & 63;
  const int ks = (idx >> 9) % KS;
  const int nt = idx / (KS * 512);
  const int co = nt * 16 + (l & 15);
  const int kglob = ks * 32 + (l >> 4) * 8 + j;
  const int tap = kglob / CINP;  // CINP is pow2
  const int cin = kglob & (CINP - 1);
  float v = 0.f;
  if (tap < 9 && cin < CIN) v = w[((size_t)co * CIN + cin) * 9 + tap];
  bp[idx] = f2bf(v);
}

// ---------------------------------------------------------------------------
// Implicit-GEMM 3x3 conv via bf16 MFMA, fp32 accumulate. 16x32 pixel tile.
// ---------------------------------------------------------------------------
template <int CIN0, int CIN1, int CINP, int COUT, bool RELU>
__global__ __launch_bounds__(256) void conv3x3_mfma(
    const float* __restrict__ in0, const float* __restrict__ in1,
    const unsigned short* __restrict__ bpack, const float* __restrict__ bias,
    float* __restrict__ out) {
  constexpr int CIN = CIN0 + CIN1;
  constexpr int NT = COUT / 16;
  constexpr int KS = (CINP == 32) ? 9 : 5;   // K-steps of 32
  constexpr int CS = CINP + 8;               // cin stride (bf16 elems)
  constexpr int TILE_BYTES = 18 * 34 * CS * 2;
  constexpr int EPI_BYTES = 4 * (16 * 4 * 33) * 4;  // 4 waves x 2112 floats
  constexpr int SMEM = (TILE_BYTES > EPI_BYTES) ? TILE_BYTES : EPI_BYTES;
  __shared__ __align__(16) char smem[SMEM];
  unsigned short* tile = (unsigned short*)smem;

  const int tid = threadIdx.x;
  const int w0 = blockIdx.x * 32, h0 = blockIdx.y * 16, b = blockIdx.z;

  // ---- stage halo'd tile, channels-last, fp32 -> bf16 ----
  {
    constexpr int PAIRS = CINP / 2;
    constexpr int TOTAL = 18 * 34 * PAIRS;
    for (int idx = tid; idx < TOTAL; idx += 256) {
      const int cp = idx / (18 * 34);
      const int rc = idx - cp * (18 * 34);
      const int r = rc / 34, c = rc - r * 34;
      const int gh = h0 + r - 1, gw = w0 + c - 1;
      const int c0 = cp * 2;
      float v0 = 0.f, v1 = 0.f;
      if ((unsigned)gh < (unsigned)H && (unsigned)gw < (unsigned)W) {
        const size_t sp = (size_t)gh * W + gw;
        if (c0 < CIN0) v0 = in0[(size_t)(b * CIN0 + c0) * HW + sp];
        else if (c0 < CIN) v0 = in1[(size_t)(b * CIN1 + (c0 - CIN0)) * HW + sp];
        const int c1 = c0 + 1;
        if (c1 < CIN0) v1 = in0[(size_t)(b * CIN0 + c1) * HW + sp];
        else if (c1 < CIN) v1 = in1[(size_t)(b * CIN1 + (c1 - CIN0)) * HW + sp];
      }
      union { unsigned int u; unsigned short s[2]; } pk;
      pk.s[0] = f2bf(v0);
      pk.s[1] = f2bf(v1);
      *(unsigned int*)&tile[(size_t)(r * 34 + c) * CS + c0] = pk.u;
    }
  }
  __syncthreads();

  // ---- K-loop ----
  const int wv = tid >> 6, lane = tid & 63;
  const int q = lane >> 4, l15 = lane & 15;
  const int rb = wv * 4;

  floatx4 acc[8][NT];
#pragma unroll
  for (int mf = 0; mf < 8; ++mf)
#pragma unroll
    for (int nt = 0; nt < NT; ++nt) acc[mf][nt] = floatx4{0.f, 0.f, 0.f, 0.f};

  for (int ks = 0; ks < KS; ++ks) {
    short8 bfrag[NT];
#pragma unroll
    for (int nt = 0; nt < NT; ++nt)
      bfrag[nt] = *(const short8*)(bpack + (size_t)(((nt * KS) + ks) * 64 + lane) * 8);

    int tap, cin0l;
    if (CINP == 32) { tap = ks; cin0l = q * 8; }
    else { tap = ks * 2 + (q >> 1); cin0l = (q & 1) * 8; if (tap > 8) tap = 8; }
    const int ky = tap / 3, kx = tap - ky * 3;
    const int baseE = ((rb + ky) * 34 + (l15 + kx)) * CS + cin0l;
    const char* aptr = smem + (size_t)baseE * 2;

#pragma unroll
    for (int mf = 0; mf < 8; ++mf) {
      constexpr int mfs[8][2] = {{0,0},{0,16},{1,0},{1,16},{2,0},{2,16},{3,0},{3,16}};
      const int off = (mfs[mf][0] * 34 + mfs[mf][1]) * CS * 2;
      const short8 af = *(const short8*)(aptr + off);
#pragma unroll
      for (int nt = 0; nt < NT; ++nt)
        acc[mf][nt] = __builtin_amdgcn_mfma_f32_16x16x32_bf16(
            af, bfrag[nt], acc[mf][nt], 0, 0, 0);
    }
  }

  __syncthreads();  // done reading tile; epilogue reuses smem

  // ---- epilogue: LDS transpose per wave, coalesced stores ----
  float* ep = (float*)smem + wv * 2112;  // 16co x 4r x (32+1)
  const int row_i = lane >> 5, colr = lane & 31;
#pragma unroll
  for (int nt = 0; nt < NT; ++nt) {
    if (nt) __syncthreads();
    const float bv = bias[nt * 16 + l15];
#pragma unroll
    for (int mf = 0; mf < 8; ++mf) {
      const int r = mf >> 1;
      const int colbase = (mf & 1) * 16 + q * 4;
#pragma unroll
      for (int rg = 0; rg < 4; ++rg) {
        float v = acc[mf][nt][rg] + bv;
        if (RELU) v = fmaxf(v, 0.f);
        ep[(l15 * 4 + r) * 33 + colbase + rg] = v;
      }
    }
    const int cog = nt * 16;
#pragma unroll
    for (int jj = 0; jj < 32; ++jj) {
      const int cr = jj * 2 + row_i;
      const int co = cr >> 2, r = cr & 3;
      const float v = ep[cr * 33 + colr];
      out[((size_t)(b * COUT + cog + co)) * HW + (size_t)(h0 + rb + r) * W + w0 + colr] = v;
    }
  }
}

// ---------------------------------------------------------------------------
// argmax over 19 channels -> float index, 4 pixels/thread (float4)
// ---------------------------------------------------------------------------
__global__ __launch_bounds__(256) void argmax_kernel(
    const float* __restrict__ x, float* __restrict__ sx) {
  const int t = blockIdx.x * 256 + threadIdx.x;  // [0, B*HW/4)
  const int b = t / (HW / 4);
  const int s4 = (t - b * (HW / 4)) * 4;
  const float* xp = x + (size_t)b * 19 * HW + s4;
  float4 bv = *(const float4*)xp;
  float ix = 0.f, iy = 0.f, iz = 0.f, iw = 0.f;
#pragma unroll
  for (int c = 1; c < 19; ++c) {
    const float4 v = *(const float4*)(xp + (size_t)c * HW);
    const float fc = (float)c;
    if (v.x > bv.x) { bv.x = v.x; ix = fc; }
    if (v.y > bv.y) { bv.y = v.y; iy = fc; }
    if (v.z > bv.z) { bv.z = v.z; iz = fc; }
    if (v.w > bv.w) { bv.w = v.w; iw = fc; }
  }
  *(float4*)(sx + (size_t)b * HW + s4) = float4{ix, iy, iz, iw};
}

// ---------------------------------------------------------------------------
// Laplacian edge, 4 pixels/thread. r[6] = cols w0-1 .. w0+4 of a row.
// ---------------------------------------------------------------------------
__device__ inline void load_row6(const float* __restrict__ plane, int hh,
                                 int w0, float r[6]) {
#pragma unroll
  for (int i = 0; i < 6; ++i) r[i] = 0.f;
  if ((unsigned)hh < (unsigned)H) {
    const float* rp = plane + (size_t)hh * W + w0;
    const float4 m = *(const float4*)rp;
    r[1] = m.x; r[2] = m.y; r[3] = m.z; r[4] = m.w;
    if (w0 > 0) r[0] = rp[-1];
    if (w0 + 4 < W) r[5] = rp[4];
  }
}

__global__ __launch_bounds__(256) void edge_kernel(
    const float* __restrict__ sx, float* __restrict__ edge) {
  const int t = blockIdx.x * 256 + threadIdx.x;
  const int b = t / (HW / 4);
  const int s4 = (t - b * (HW / 4)) * 4;
  const int h = s4 / W, w0 = s4 - h * W;
  const float* sp = sx + (size_t)b * HW;
  float r0[6], r1[6], r2[6];
  load_row6(sp, h - 1, w0, r0);
  load_row6(sp, h, w0, r1);
  load_row6(sp, h + 1, w0, r2);
  float o[4];
#pragma unroll
  for (int k = 0; k < 4; ++k)
    o[k] = r0[k] + r0[k + 1] + r0[k + 2] + r1[k] + r1[k + 2] + r2[k] +
           r2[k + 1] + r2[k + 2] - 8.f * r1[k + 1];
  *(float4*)(edge + (size_t)b * HW + s4) = float4{o[0], o[1], o[2], o[3]};
}

// 1x1 conv 16 -> 19, 4 pixels/thread.
__global__ __launch_bounds__(256) void conv1x1_16_19(
    const float* __restrict__ in, const float* __restrict__ wgt,
    const float* __restrict__ bias, float* __restrict__ out) {
  const int t = blockIdx.x * 256 + threadIdx.x;
  const int b = t / (HW / 4);
  const int s4 = (t - b * (HW / 4)) * 4;
  float4 xi[16];
#pragma unroll
  for (int c = 0; c < 16; ++c)
    xi[c] = *(const float4*)(in + (size_t)(b * 16 + c) * HW + s4);
#pragma unroll
  for (int co = 0; co < 19; ++co) {
    const float bv = bias[co];
    float ax = bv, ay = bv, az = bv, aw = bv;
#pragma unroll
    for (int c = 0; c < 16; ++c) {
      const float wv = wgt[co * 16 + c];
      ax = fmaf(xi[c].x, wv, ax);
      ay = fmaf(xi[c].y, wv, ay);
      az = fmaf(xi[c].z, wv, az);
      aw = fmaf(xi[c].w, wv, aw);
    }
    *(float4*)(out + (size_t)(b * 19 + co) * HW + s4) = float4{ax, ay, az, aw};
  }
}

// 1x1 conv 32 -> 11 + sigmoid + normalize, 2 pixels/thread (VGPR pressure).
__global__ __launch_bounds__(256) void guide3_kernel(
    const float* __restrict__ in, const float* __restrict__ wgt,
    const float* __restrict__ bias, float* __restrict__ gf) {
  const int t = blockIdx.x * 256 + threadIdx.x;
  const int b = t / (HW / 2);
  const int s2 = (t - b * (HW / 2)) * 2;
  float2 xi[32];
#pragma unroll
  for (int c = 0; c < 32; ++c)
    xi[c] = *(const float2*)(in + (size_t)(b * 32 + c) * HW + s2);
  float gx[11], gy[11];
  float sx_ = 0.f, sy_ = 0.f;
#pragma unroll
  for (int co = 0; co < 11; ++co) {
    const float bv = bias[co];
    float ax = bv, ay = bv;
#pragma unroll
    for (int c = 0; c < 32; ++c) {
      const float wv = wgt[co * 32 + c];
      ax = fmaf(xi[c].x, wv, ax);
      ay = fmaf(xi[c].y, wv, ay);
    }
    gx[co] = 1.f / (1.f + expf(-ax));
    gy[co] = 1.f / (1.f + expf(-ay));
    sx_ += gx[co];
    sy_ += gy[co];
  }
  const float invx = 1.f / (sx_ + 1e-9f), invy = 1.f / (sy_ + 1e-9f);
#pragma unroll
  for (int co = 0; co < 11; ++co)
    *(float2*)(gf + (size_t)(b * 11 + co) * HW + s2) =
        float2{gx[co] * invx, gy[co] * invy};
}

// ---------------------------------------------------------------------------
// combine, 4 pixels/thread: gf held in registers across the 19-channel loop.
// out[c] = gf0*x + sum_{m=1..8} gf_m*x(shift_m) + gf10*intra  (gf9: zero chan)
// ---------------------------------------------------------------------------
__global__ __launch_bounds__(256) void combine_kernel(
    const float* __restrict__ x, const float* __restrict__ intra,
    const float* __restrict__ gf, float* __restrict__ out) {
  const int t = blockIdx.x * 256 + threadIdx.x;  // [0, B*HW/4)
  const int b = t / (HW / 4);
  const int s4 = (t - b * (HW / 4)) * 4;
  const int h = s4 / W, w0 = s4 - h * W;
  const float* gp = gf + (size_t)b * 11 * HW + s4;

  float g[11][4];
#pragma unroll
  for (int m = 0; m < 11; ++m) {
    if (m == 9) continue;  // all-zero shift channel
    const float4 v = *(const float4*)(gp + (size_t)m * HW);
    g[m][0] = v.x; g[m][1] = v.y; g[m][2] = v.z; g[m][3] = v.w;
  }

  for (int c = 0; c < 19; ++c) {
    const float* xc = x + (size_t)(b * 19 + c) * HW;
    float r0[6], r1[6], r2[6];
    load_row6(xc, h - 1, w0, r0);
    load_row6(xc, h, w0, r1);
    load_row6(xc, h + 1, w0, r2);
    const float4 it = *(const float4*)(intra + (size_t)(b * 19 + c) * HW + s4);
    const float itv[4] = {it.x, it.y, it.z, it.w};
    float o[4];
#pragma unroll
    for (int k = 0; k < 4; ++k) {
      float a = g[0][k] * r1[k + 1];
      a = fmaf(g[1][k], r0[k], a);
      a = fmaf(g[2][k], r0[k + 1], a);
      a = fmaf(g[3][k], r0[k + 2], a);
      a = fmaf(g[4][k], r1[k], a);
      a = fmaf(g[5][k], r1[k + 2], a);
      a = fmaf(g[6][k], r2[k], a);
      a = fmaf(g[7][k], r2[k + 1], a);
      a = fmaf(g[8][k], r2[k + 2], a);
      a = fmaf(g[10][k], itv[k], a);
      o[k] = a;
    }
    *(float4*)(out + (size_t)(b * 19 + c) * HW + s4) =
        float4{o[0], o[1], o[2], o[3]};
  }
}

// ---------------------------------------------------------------------------
extern "C" void kernel_launch(void* const* d_in, const int* in_sizes, int n_in,
                              void* d_out, int out_size, void* d_ws,
                              size_t ws_size, hipStream_t stream) {
  const float* x     = (const float*)d_in[0];
  const float* image = (const float*)d_in[1];
  const float* iw1 = (const float*)d_in[2];
  const float* ib1 = (const float*)d_in[3];
  const float* iw2 = (const float*)d_in[4];
  const float* ib2 = (const float*)d_in[5];
  const float* iw3 = (const float*)d_in[6];
  const float* ib3 = (const float*)d_in[7];
  const float* gw1 = (const float*)d_in[8];
  const float* gb1 = (const float*)d_in[9];
  const float* gw2 = (const float*)d_in[10];
  const float* gb2 = (const float*)d_in[11];
  const float* gw3 = (const float*)d_in[12];
  const float* gb3 = (const float*)d_in[13];

  float* ws = (float*)d_ws;
  float* f1    = ws;                           // 2*16*HW
  float* f2    = ws + (size_t)2 * 16 * HW;     // 2*16*HW
  float* intra = ws + (size_t)4 * 16 * HW;     // 2*19*HW
  float* sx    = intra + (size_t)2 * 19 * HW;  // 2*HW (argmax map, then Bpacks)
  float* g1    = ws;                           // 2*32*HW (over f1,f2)
  float* g2    = sx + (size_t)2 * HW;          // 2*32*HW

  unsigned short* bp_ic2 = (unsigned short*)sx;          // 2560 elems
  unsigned short* bp_gc1 = (unsigned short*)sx + 4096;   // 9216 elems
  unsigned short* bp_gc2 = (unsigned short*)sx + 16384;  // 9216 elems

  float* out0 = (float*)d_out;               // (2,19,512,512)
  float* gfo  = out0 + (size_t)2 * 19 * HW;  // (2,11,1,512,512)
  float* edg  = gfo + (size_t)2 * 11 * HW;   // (2,1,512,512)

  const dim3 blk16(16, 16);
  const dim3 grd16(W / 16, H / 16, B);
  const dim3 blkM(256);
  const dim3 grdM(W / 32, H / 16, B);
  const int flat4 = (B * HW / 4) / 256;  // 512
  const int flat2 = (B * HW / 2) / 256;  // 1024

  argmax_kernel<<<flat4, 256, 0, stream>>>(x, sx);
  edge_kernel<<<flat4, 256, 0, stream>>>(sx, edg);

  repack_w<16, 16, 16, 5><<<10, 256, 0, stream>>>(iw2, bp_ic2);
  repack_w<20, 32, 32, 9><<<36, 256, 0, stream>>>(gw1, bp_gc1);
  repack_w<32, 32, 32, 9><<<36, 256, 0, stream>>>(gw2, bp_gc2);

  conv3x3_fp32<3, 16, true><<<grd16, blk16, 0, stream>>>(image, iw1, ib1, f1);
  conv3x3_mfma<16, 0, 16, 16, true><<<grdM, blkM, 0, stream>>>(f1, nullptr, bp_ic2, ib2, f2);
  conv1x1_16_19<<<flat4, 256, 0, stream>>>(f2, iw3, ib3, intra);
  conv3x3_mfma<19, 1, 32, 32, true><<<grdM, blkM, 0, stream>>>(intra, edg, bp_gc1, gb1, g1);
  conv3x3_mfma<32, 0, 32, 32, true><<<grdM, blkM, 0, stream>>>(g1, nullptr, bp_gc2, gb2, g2);
  guide3_kernel<<<flat2, 256, 0, stream>>>(g2, gw3, gb3, gfo);
  combine_kernel<<<(B * HW / 4) / 256, 256, 0, stream>>>(x, intra, gfo, out0);
}

// Round 5
// 309.429 us; speedup vs baseline: 2.9683x; 1.0674x over previous
//
#include <hip/hip_runtime.h>
#include <math.h>

// Problem constants (fixed by setup_inputs): B=2, C=19, H=W=512, fp32 in/out.
constexpr int H = 512, W = 512, B = 2;
constexpr int HW = H * W;

typedef __attribute__((ext_vector_type(8))) short short8;
typedef __attribute__((ext_vector_type(4))) float floatx4;
typedef __attribute__((ext_vector_type(4))) unsigned int uint4v;

__device__ inline unsigned short f2bf(float f) {
  union { float f; unsigned int u; } x{f};
  const unsigned int u = x.u;
  return (unsigned short)((u + 0x7FFFu + ((u >> 16) & 1u)) >> 16);
}
__device__ inline float bf2f(unsigned short s) {
  union { unsigned int u; float f; } x;
  x.u = (unsigned int)s << 16;
  return x.f;
}

// ---------------------------------------------------------------------------
// fp32 tiled 3x3 conv 3->16, writes bf16 NHWC packed output [B][H][W][16].
// ---------------------------------------------------------------------------
template <int CIN, int COUT, bool RELU>
__global__ __launch_bounds__(256) void conv3x3_fp32_pack(
    const float* __restrict__ in0, const float* __restrict__ wgt,
    const float* __restrict__ bias, unsigned short* __restrict__ outp) {
  constexpr int TS = 16, TH = 18, LDW = 20;
  __shared__ float tile[CIN][TH][LDW];
  const int tx = threadIdx.x, ty = threadIdx.y;
  const int tid = ty * 16 + tx;
  const int w0 = blockIdx.x * TS, h0 = blockIdx.y * TS, b = blockIdx.z;

  for (int idx = tid; idx < CIN * TH * TH; idx += 256) {
    const int cin = idx / (TH * TH);
    const int rem = idx - cin * (TH * TH);
    const int r = rem / TH, c = rem - r * TH;
    const int gh = h0 + r - 1, gw = w0 + c - 1;
    float v = 0.f;
    if ((unsigned)gh < (unsigned)H && (unsigned)gw < (unsigned)W)
      v = in0[(size_t)(b * CIN + cin) * HW + gh * W + gw];
    tile[cin][r][c] = v;
  }
  __syncthreads();

  float acc[COUT];
#pragma unroll
  for (int co = 0; co < COUT; ++co) acc[co] = bias[co];
  for (int cin = 0; cin < CIN; ++cin) {
#pragma unroll
    for (int t = 0; t < 9; ++t) {
      const int ky = t / 3, kx = t - ky * 3;
      const float v = tile[cin][ty + ky][tx + kx];
#pragma unroll
      for (int co = 0; co < COUT; ++co)
        acc[co] = fmaf(v, wgt[(co * CIN + cin) * 9 + t], acc[co]);
    }
  }
  const int oh = h0 + ty, ow = w0 + tx;
  unsigned int pk[COUT / 2];
#pragma unroll
  for (int c2 = 0; c2 < COUT / 2; ++c2) {
    float a0 = acc[2 * c2], a1 = acc[2 * c2 + 1];
    if (RELU) { a0 = fmaxf(a0, 0.f); a1 = fmaxf(a1, 0.f); }
    pk[c2] = (unsigned)f2bf(a0) | ((unsigned)f2bf(a1) << 16);
  }
  unsigned short* dst = outp + ((size_t)(b * H + oh) * W + ow) * COUT;
#pragma unroll
  for (int u = 0; u < COUT / 8; ++u)
    *(uint4v*)(dst + u * 8) = uint4v{pk[u * 4], pk[u * 4 + 1], pk[u * 4 + 2], pk[u * 4 + 3]};
}

// ---------------------------------------------------------------------------
// Weight repack into B-fragment order for mfma_f32_16x16x32_bf16.
// k = tap*CINP + cin (CINP mult of 8 so 8-runs stay within one tap).
// ---------------------------------------------------------------------------
template <int CIN, int CINP, int COUT, int KS>
__global__ __launch_bounds__(256) void repack_w(
    const float* __restrict__ w, unsigned short* __restrict__ bp) {
  constexpr int NT = COUT / 16;
  const int idx = blockIdx.x * 256 + threadIdx.x;
  if (idx >= NT * KS * 512) return;
  const int j = idx & 7;
  const int l = (idx >> 3) & 63;
  const int ks = (idx >> 9) % KS;
  const int nt = idx / (KS * 512);
  const int co = nt * 16 + (l & 15);
  const int kglob = ks * 32 + (l >> 4) * 8 + j;
  const int tap = kglob / CINP;
  const int cin = kglob % CINP;
  float v = 0.f;
  if (tap < 9 && cin < CIN) v = w[((size_t)co * CIN + cin) * 9 + tap];
  bp[idx] = f2bf(v);
}

// ---------------------------------------------------------------------------
// Implicit-GEMM 3x3 conv via bf16 MFMA. Packed bf16 NHWC input [H][W][CINP].
// 16x32 pixel tile / block (4 waves, 4 rows each). Epilogue modes:
//   0 = pack: bias+relu, write bf16 NHWC [H][W][NT*16]
//   1 = fused 1x1 16->19 (+b2), write bf16 NHWC [H][W][24] (ch19..23 = 0)
//   2 = fused 1x1 32->11 (+b2) + sigmoid + normalize, write fp32 planes [11][HW]
// EDGE19: staging overwrites channel 19 with bf16(edg[pixel]).
// ---------------------------------------------------------------------------
template <int CINP, int KS, int NT, int EPI, bool EDGE19, bool RELU>
__global__ __launch_bounds__(256) void conv3x3_mfma(
    const unsigned short* __restrict__ inp, const float* __restrict__ edg,
    const unsigned short* __restrict__ bpack, const float* __restrict__ bias,
    const float* __restrict__ w2, const float* __restrict__ b2,
    void* __restrict__ outv) {
  constexpr int CS = (CINP == 16) ? 24 : 40;  // LDS cin stride (16B-mult, low-conflict)
  constexpr int TILE_BYTES = 18 * 34 * CS * 2;
  constexpr int EPI_BYTES = 4 * 2112 * 4;  // 4 waves x (16*4*33) floats
  constexpr int SMEM = (TILE_BYTES > EPI_BYTES) ? TILE_BYTES : EPI_BYTES;
  __shared__ __align__(16) char smem[SMEM];
  unsigned short* tile = (unsigned short*)smem;

  const int tid = threadIdx.x;
  const int w0 = blockIdx.x * 32, h0 = blockIdx.y * 16, b = blockIdx.z;

  // ---- stage halo'd tile: packed pixel copy (dwordx4), zero for OOB ----
  for (int idx = tid; idx < 18 * 34; idx += 256) {
    const int r = idx / 34, c = idx - r * 34;
    const int gh = h0 + r - 1, gw = w0 + c - 1;
    unsigned short* dst = tile + (size_t)(r * 34 + c) * CS;
    if ((unsigned)gh < (unsigned)H && (unsigned)gw < (unsigned)W) {
      const unsigned short* src = inp + ((size_t)(b * H + gh) * W + gw) * CINP;
#pragma unroll
      for (int u = 0; u < CINP / 8; ++u)
        *(uint4v*)(dst + u * 8) = *(const uint4v*)(src + u * 8);
      if (EDGE19) dst[19] = f2bf(edg[(size_t)b * HW + gh * W + gw]);
    } else {
#pragma unroll
      for (int u = 0; u < CINP / 8; ++u)
        *(uint4v*)(dst + u * 8) = uint4v{0, 0, 0, 0};
    }
  }
  __syncthreads();

  // ---- K-loop ----
  const int wv = tid >> 6, lane = tid & 63;
  const int q = lane >> 4, l15 = lane & 15;
  const int rb = wv * 4;

  floatx4 acc[8][NT];
#pragma unroll
  for (int mf = 0; mf < 8; ++mf)
#pragma unroll
    for (int nt = 0; nt < NT; ++nt) acc[mf][nt] = floatx4{0.f, 0.f, 0.f, 0.f};

  for (int ks = 0; ks < KS; ++ks) {
    short8 bfrag[NT];
#pragma unroll
    for (int nt = 0; nt < NT; ++nt)
      bfrag[nt] = *(const short8*)(bpack + (size_t)(((nt * KS) + ks) * 64 + lane) * 8);

    const int kbase = ks * 32 + q * 8;
    int tap = kbase / CINP;
    const int cinl = kbase % CINP;
    if (tap > 8) tap = 8;  // zero-weight pad region; any in-range addr ok
    const int ky = tap / 3, kx = tap - ky * 3;
    const char* aptr =
        smem + (size_t)(((rb + ky) * 34 + (l15 + kx)) * CS + cinl) * 2;

#pragma unroll
    for (int mf = 0; mf < 8; ++mf) {
      constexpr int mfs[8][2] = {{0,0},{0,16},{1,0},{1,16},{2,0},{2,16},{3,0},{3,16}};
      const int off = (mfs[mf][0] * 34 + mfs[mf][1]) * CS * 2;
      const short8 af = *(const short8*)(aptr + off);
#pragma unroll
      for (int nt = 0; nt < NT; ++nt)
        acc[mf][nt] = __builtin_amdgcn_mfma_f32_16x16x32_bf16(
            af, bfrag[nt], acc[mf][nt], 0, 0, 0);
    }
  }

  __syncthreads();  // all waves done with tile; per-wave epilogue regions below

  float* ep = (float*)smem + wv * 2112;  // [16ch][4row][33col] per wave

  // thread's 2 epilogue pixels: p = k*64+lane -> row=p>>5 (0..3), col=p&31
#define EP_WRITE(NTI)                                                     \
  {                                                                       \
    const float bv = bias[(NTI)*16 + l15];                                \
    _Pragma("unroll") for (int mf = 0; mf < 8; ++mf) {                    \
      const int r_ = mf >> 1, colb_ = (mf & 1) * 16 + q * 4;              \
      _Pragma("unroll") for (int rg = 0; rg < 4; ++rg) {                  \
        float v_ = acc[mf][(NTI)][rg] + bv;                               \
        if (RELU) v_ = fmaxf(v_, 0.f);                                    \
        ep[(l15 * 4 + r_) * 33 + colb_ + rg] = v_;                        \
      }                                                                   \
    }                                                                     \
  }

  if (EPI == 0) {
    // ---- pack epilogue: bf16 NHWC [H][W][NT*16] ----
    unsigned int pk[2][NT * 8];
#pragma unroll
    for (int nt = 0; nt < NT; ++nt) {
      EP_WRITE(nt);
      __builtin_amdgcn_wave_barrier();
#pragma unroll
      for (int k = 0; k < 2; ++k) {
        const int p = k * 64 + lane, row = p >> 5, col = p & 31;
#pragma unroll
        for (int c2 = 0; c2 < 8; ++c2) {
          const float a0 = ep[((c2 * 2) * 4 + row) * 33 + col];
          const float a1 = ep[((c2 * 2 + 1) * 4 + row) * 33 + col];
          pk[k][nt * 8 + c2] = (unsigned)f2bf(a0) | ((unsigned)f2bf(a1) << 16);
        }
      }
      __builtin_amdgcn_wave_barrier();
    }
    unsigned short* op = (unsigned short*)outv;
#pragma unroll
    for (int k = 0; k < 2; ++k) {
      const int p = k * 64 + lane, row = p >> 5, col = p & 31;
      unsigned short* dst =
          op + ((size_t)(b * H + h0 + rb + row) * W + w0 + col) * (NT * 16);
#pragma unroll
      for (int u = 0; u < NT * 2; ++u)
        *(uint4v*)(dst + u * 8) =
            uint4v{pk[k][u * 4], pk[k][u * 4 + 1], pk[k][u * 4 + 2], pk[k][u * 4 + 3]};
    }
  } else if (EPI == 1) {
    // ---- fused 1x1 16->19 -> packed bf16 [H][W][24], ch19..23 zero ----
    float accp[2][19];
#pragma unroll
    for (int k = 0; k < 2; ++k)
#pragma unroll
      for (int co = 0; co < 19; ++co) accp[k][co] = b2[co];
    EP_WRITE(0);
    __builtin_amdgcn_wave_barrier();
#pragma unroll
    for (int k = 0; k < 2; ++k) {
      const int p = k * 64 + lane, row = p >> 5, col = p & 31;
#pragma unroll
      for (int ci = 0; ci < 16; ++ci) {
        const float v = ep[(ci * 4 + row) * 33 + col];
#pragma unroll
        for (int co = 0; co < 19; ++co)
          accp[k][co] = fmaf(v, w2[co * 16 + ci], accp[k][co]);
      }
    }
    unsigned short* op = (unsigned short*)outv;
#pragma unroll
    for (int k = 0; k < 2; ++k) {
      const int p = k * 64 + lane, row = p >> 5, col = p & 31;
      unsigned int pk[12];
#pragma unroll
      for (int j = 0; j < 9; ++j)
        pk[j] = (unsigned)f2bf(accp[k][2 * j]) | ((unsigned)f2bf(accp[k][2 * j + 1]) << 16);
      pk[9] = (unsigned)f2bf(accp[k][18]);
      pk[10] = 0; pk[11] = 0;
      unsigned short* dst =
          op + ((size_t)(b * H + h0 + rb + row) * W + w0 + col) * 24;
#pragma unroll
      for (int u = 0; u < 3; ++u)
        *(uint4v*)(dst + u * 8) = uint4v{pk[u * 4], pk[u * 4 + 1], pk[u * 4 + 2], pk[u * 4 + 3]};
    }
  } else {
    // ---- fused 1x1 32->11 + sigmoid + normalize -> fp32 planes [11][HW] ----
    float accp[2][11];
#pragma unroll
    for (int k = 0; k < 2; ++k)
#pragma unroll
      for (int co = 0; co < 11; ++co) accp[k][co] = b2[co];
#pragma unroll
    for (int nt = 0; nt < NT; ++nt) {
      EP_WRITE(nt);
      __builtin_amdgcn_wave_barrier();
#pragma unroll
      for (int k = 0; k < 2; ++k) {
        const int p = k * 64 + lane, row = p >> 5, col = p & 31;
#pragma unroll
        for (int ci = 0; ci < 16; ++ci) {
          const float v = ep[(ci * 4 + row) * 33 + col];
#pragma unroll
          for (int co = 0; co < 11; ++co)
            accp[k][co] = fmaf(v, w2[co * 32 + nt * 16 + ci], accp[k][co]);
        }
      }
      __builtin_amdgcn_wave_barrier();
    }
    float* gfo = (float*)outv;
#pragma unroll
    for (int k = 0; k < 2; ++k) {
      const int p = k * 64 + lane, row = p >> 5, col = p & 31;
      float gg[11], s = 0.f;
#pragma unroll
      for (int co = 0; co < 11; ++co) {
        gg[co] = 1.f / (1.f + expf(-accp[k][co]));
        s += gg[co];
      }
      const float inv = 1.f / (s + 1e-9f);
      const size_t pix = (size_t)(h0 + rb + row) * W + w0 + col;
#pragma unroll
      for (int co = 0; co < 11; ++co)
        gfo[(size_t)(b * 11 + co) * HW + pix] = gg[co] * inv;
    }
  }
#undef EP_WRITE
}

// ---------------------------------------------------------------------------
// argmax over 19 channels -> float index, 4 pixels/thread
// ---------------------------------------------------------------------------
__global__ __launch_bounds__(256) void argmax_kernel(
    const float* __restrict__ x, float* __restrict__ sx) {
  const int t = blockIdx.x * 256 + threadIdx.x;
  const int b = t / (HW / 4);
  const int s4 = (t - b * (HW / 4)) * 4;
  const float* xp = x + (size_t)b * 19 * HW + s4;
  float4 bv = *(const float4*)xp;
  float ix = 0.f, iy = 0.f, iz = 0.f, iw = 0.f;
#pragma unroll
  for (int c = 1; c < 19; ++c) {
    const float4 v = *(const float4*)(xp + (size_t)c * HW);
    const float fc = (float)c;
    if (v.x > bv.x) { bv.x = v.x; ix = fc; }
    if (v.y > bv.y) { bv.y = v.y; iy = fc; }
    if (v.z > bv.z) { bv.z = v.z; iz = fc; }
    if (v.w > bv.w) { bv.w = v.w; iw = fc; }
  }
  *(float4*)(sx + (size_t)b * HW + s4) = float4{ix, iy, iz, iw};
}

__device__ inline void load_row6(const float* __restrict__ plane, int hh,
                                 int w0, float r[6]) {
#pragma unroll
  for (int i = 0; i < 6; ++i) r[i] = 0.f;
  if ((unsigned)hh < (unsigned)H) {
    const float* rp = plane + (size_t)hh * W + w0;
    const float4 m = *(const float4*)rp;
    r[1] = m.x; r[2] = m.y; r[3] = m.z; r[4] = m.w;
    if (w0 > 0) r[0] = rp[-1];
    if (w0 + 4 < W) r[5] = rp[4];
  }
}

__global__ __launch_bounds__(256) void edge_kernel(
    const float* __restrict__ sx, float* __restrict__ edge) {
  const int t = blockIdx.x * 256 + threadIdx.x;
  const int b = t / (HW / 4);
  const int s4 = (t - b * (HW / 4)) * 4;
  const int h = s4 / W, w0 = s4 - h * W;
  const float* sp = sx + (size_t)b * HW;
  float r0[6], r1[6], r2[6];
  load_row6(sp, h - 1, w0, r0);
  load_row6(sp, h, w0, r1);
  load_row6(sp, h + 1, w0, r2);
  float o[4];
#pragma unroll
  for (int k = 0; k < 4; ++k)
    o[k] = r0[k] + r0[k + 1] + r0[k + 2] + r1[k] + r1[k + 2] + r2[k] +
           r2[k + 1] + r2[k + 2] - 8.f * r1[k + 1];
  *(float4*)(edge + (size_t)b * HW + s4) = float4{o[0], o[1], o[2], o[3]};
}

// ---------------------------------------------------------------------------
// combine, 4 pixels/thread; intra read from packed bf16 [H][W][24].
// ---------------------------------------------------------------------------
__global__ __launch_bounds__(256) void combine_kernel(
    const float* __restrict__ x, const unsigned short* __restrict__ intp,
    const float* __restrict__ gf, float* __restrict__ out) {
  const int t = blockIdx.x * 256 + threadIdx.x;
  const int b = t / (HW / 4);
  const int s4 = (t - b * (HW / 4)) * 4;
  const int h = s4 / W, w0 = s4 - h * W;
  const float* gp = gf + (size_t)b * 11 * HW + s4;

  float g[11][4];
#pragma unroll
  for (int m = 0; m < 11; ++m) {
    if (m == 9) continue;  // all-zero shift channel
    const float4 v = *(const float4*)(gp + (size_t)m * HW);
    g[m][0] = v.x; g[m][1] = v.y; g[m][2] = v.z; g[m][3] = v.w;
  }

  const unsigned short* ip = intp + ((size_t)b * HW + s4) * 24;
  for (int c = 0; c < 19; ++c) {
    const float* xc = x + (size_t)(b * 19 + c) * HW;
    float r0[6], r1[6], r2[6];
    load_row6(xc, h - 1, w0, r0);
    load_row6(xc, h, w0, r1);
    load_row6(xc, h + 1, w0, r2);
    float o[4];
#pragma unroll
    for (int k = 0; k < 4; ++k) {
      const float itv = bf2f(ip[(size_t)k * 24 + c]);
      float a = g[0][k] * r1[k + 1];
      a = fmaf(g[1][k], r0[k], a);
      a = fmaf(g[2][k], r0[k + 1], a);
      a = fmaf(g[3][k], r0[k + 2], a);
      a = fmaf(g[4][k], r1[k], a);
      a = fmaf(g[5][k], r1[k + 2], a);
      a = fmaf(g[6][k], r2[k], a);
      a = fmaf(g[7][k], r2[k + 1], a);
      a = fmaf(g[8][k], r2[k + 2], a);
      a = fmaf(g[10][k], itv, a);
      o[k] = a;
    }
    *(float4*)(out + (size_t)(b * 19 + c) * HW + s4) =
        float4{o[0], o[1], o[2], o[3]};
  }
}

// ---------------------------------------------------------------------------
extern "C" void kernel_launch(void* const* d_in, const int* in_sizes, int n_in,
                              void* d_out, int out_size, void* d_ws,
                              size_t ws_size, hipStream_t stream) {
  const float* x     = (const float*)d_in[0];
  const float* image = (const float*)d_in[1];
  const float* iw1 = (const float*)d_in[2];
  const float* ib1 = (const float*)d_in[3];
  const float* iw2 = (const float*)d_in[4];
  const float* ib2 = (const float*)d_in[5];
  const float* iw3 = (const float*)d_in[6];
  const float* ib3 = (const float*)d_in[7];
  const float* gw1 = (const float*)d_in[8];
  const float* gb1 = (const float*)d_in[9];
  const float* gw2 = (const float*)d_in[10];
  const float* gb2 = (const float*)d_in[11];
  const float* gw3 = (const float*)d_in[12];
  const float* gb3 = (const float*)d_in[13];

  // Workspace layout in FLOAT units — sizes: f1p = 2*HW*16 u16 = 16*HW floats,
  // intp = 2*HW*24 u16 = 24*HW floats, g1p = 2*HW*32 u16 = 32*HW floats.
  // (Round-4 bug: these were spaced 8/12/16*HW apart -> overlapping buffers.)
  float* ws = (float*)d_ws;
  float* sx = ws;                                                  // [0, 2*HW)
  unsigned short* f1p  = (unsigned short*)(ws + (size_t)2 * HW);   // [2, 18)
  unsigned short* intp = (unsigned short*)(ws + (size_t)18 * HW);  // [18, 42)
  unsigned short* g1p  = (unsigned short*)(ws + (size_t)42 * HW);  // [42, 74)
  unsigned short* bp_ic2 = (unsigned short*)(ws + (size_t)74 * HW);  // 2560
  unsigned short* bp_gc1 = bp_ic2 + 4096;                            // 7168
  unsigned short* bp_gc2 = bp_gc1 + 12288;                           // 9216

  float* out0 = (float*)d_out;               // (2,19,512,512)
  float* gfo  = out0 + (size_t)2 * 19 * HW;  // (2,11,1,512,512)
  float* edg  = gfo + (size_t)2 * 11 * HW;   // (2,1,512,512)

  const dim3 blk16(16, 16);
  const dim3 grd16(W / 16, H / 16, B);
  const dim3 grdM(W / 32, H / 16, B);
  const int flat4 = (B * HW / 4) / 256;  // 512

  argmax_kernel<<<flat4, 256, 0, stream>>>(x, sx);
  edge_kernel<<<flat4, 256, 0, stream>>>(sx, edg);

  repack_w<16, 16, 16, 5><<<10, 256, 0, stream>>>(iw2, bp_ic2);
  repack_w<20, 24, 32, 7><<<28, 256, 0, stream>>>(gw1, bp_gc1);
  repack_w<32, 32, 32, 9><<<36, 256, 0, stream>>>(gw2, bp_gc2);

  conv3x3_fp32_pack<3, 16, true><<<grd16, blk16, 0, stream>>>(image, iw1, ib1, f1p);
  // intra conv2 (16->16) + fused 1x1 16->19 -> packed intra [H][W][24]
  conv3x3_mfma<16, 5, 1, 1, false, true><<<grdM, 256, 0, stream>>>(
      f1p, nullptr, bp_ic2, ib2, iw3, ib3, intp);
  // guide conv1 (20->32, edge in ch19) -> packed g1 [H][W][32]
  conv3x3_mfma<24, 7, 2, 0, true, true><<<grdM, 256, 0, stream>>>(
      intp, edg, bp_gc1, gb1, nullptr, nullptr, g1p);
  // guide conv2 (32->32) + fused 1x1 32->11 + sigmoid + norm -> gfo
  conv3x3_mfma<32, 9, 2, 2, false, true><<<grdM, 256, 0, stream>>>(
      g1p, nullptr, bp_gc2, gb2, gw3, gb3, gfo);

  combine_kernel<<<flat4, 256, 0, stream>>>(x, intp, gfo, out0);
}

// Round 6
// 284.450 us; speedup vs baseline: 3.2289x; 1.0878x over previous
//
#include <hip/hip_runtime.h>
#include <math.h>

// Problem constants (fixed by setup_inputs): B=2, C=19, H=W=512, fp32 in/out.
constexpr int H = 512, W = 512, B = 2;
constexpr int HW = H * W;

typedef __attribute__((ext_vector_type(8))) short short8;
typedef __attribute__((ext_vector_type(4))) float floatx4;
typedef __attribute__((ext_vector_type(4))) unsigned int uint4v;

__device__ inline unsigned short f2bf(float f) {
  union { float f; unsigned int u; } x{f};
  const unsigned int u = x.u;
  return (unsigned short)((u + 0x7FFFu + ((u >> 16) & 1u)) >> 16);
}
__device__ inline float bf2f(unsigned short s) {
  union { unsigned int u; float f; } x;
  x.u = (unsigned int)s << 16;
  return x.f;
}
// unpack packed bf16 pair (one dword) -> two floats
__device__ inline void unpk2(unsigned int u, float& lo, float& hi) {
  union { unsigned int u; float f; } a, b;
  a.u = u << 16;
  b.u = u & 0xffff0000u;
  lo = a.f;
  hi = b.f;
}

// ---------------------------------------------------------------------------
// fp32 tiled 3x3 conv 3->16, writes bf16 NHWC packed output [B][H][W][16].
// ---------------------------------------------------------------------------
template <int CIN, int COUT, bool RELU>
__global__ __launch_bounds__(256) void conv3x3_fp32_pack(
    const float* __restrict__ in0, const float* __restrict__ wgt,
    const float* __restrict__ bias, unsigned short* __restrict__ outp) {
  constexpr int TS = 16, TH = 18, LDW = 20;
  __shared__ float tile[CIN][TH][LDW];
  const int tx = threadIdx.x, ty = threadIdx.y;
  const int tid = ty * 16 + tx;
  const int w0 = blockIdx.x * TS, h0 = blockIdx.y * TS, b = blockIdx.z;

  for (int idx = tid; idx < CIN * TH * TH; idx += 256) {
    const int cin = idx / (TH * TH);
    const int rem = idx - cin * (TH * TH);
    const int r = rem / TH, c = rem - r * TH;
    const int gh = h0 + r - 1, gw = w0 + c - 1;
    float v = 0.f;
    if ((unsigned)gh < (unsigned)H && (unsigned)gw < (unsigned)W)
      v = in0[(size_t)(b * CIN + cin) * HW + gh * W + gw];
    tile[cin][r][c] = v;
  }
  __syncthreads();

  float acc[COUT];
#pragma unroll
  for (int co = 0; co < COUT; ++co) acc[co] = bias[co];
  for (int cin = 0; cin < CIN; ++cin) {
#pragma unroll
    for (int t = 0; t < 9; ++t) {
      const int ky = t / 3, kx = t - ky * 3;
      const float v = tile[cin][ty + ky][tx + kx];
#pragma unroll
      for (int co = 0; co < COUT; ++co)
        acc[co] = fmaf(v, wgt[(co * CIN + cin) * 9 + t], acc[co]);
    }
  }
  const int oh = h0 + ty, ow = w0 + tx;
  unsigned int pk[COUT / 2];
#pragma unroll
  for (int c2 = 0; c2 < COUT / 2; ++c2) {
    float a0 = acc[2 * c2], a1 = acc[2 * c2 + 1];
    if (RELU) { a0 = fmaxf(a0, 0.f); a1 = fmaxf(a1, 0.f); }
    pk[c2] = (unsigned)f2bf(a0) | ((unsigned)f2bf(a1) << 16);
  }
  unsigned short* dst = outp + ((size_t)(b * H + oh) * W + ow) * COUT;
#pragma unroll
  for (int u = 0; u < COUT / 8; ++u)
    *(uint4v*)(dst + u * 8) = uint4v{pk[u * 4], pk[u * 4 + 1], pk[u * 4 + 2], pk[u * 4 + 3]};
}

// ---------------------------------------------------------------------------
// Weight repack into B-fragment order for mfma_f32_16x16x32_bf16.
// k = tap*CINP + cin (CINP mult of 8 so 8-runs stay within one tap).
// ---------------------------------------------------------------------------
template <int CIN, int CINP, int COUT, int KS>
__global__ __launch_bounds__(256) void repack_w(
    const float* __restrict__ w, unsigned short* __restrict__ bp) {
  constexpr int NT = COUT / 16;
  const int idx = blockIdx.x * 256 + threadIdx.x;
  if (idx >= NT * KS * 512) return;
  const int j = idx & 7;
  const int l = (idx >> 3) & 63;
  const int ks = (idx >> 9) % KS;
  const int nt = idx / (KS * 512);
  const int co = nt * 16 + (l & 15);
  const int kglob = ks * 32 + (l >> 4) * 8 + j;
  const int tap = kglob / CINP;
  const int cin = kglob % CINP;
  float v = 0.f;
  if (tap < 9 && cin < CIN) v = w[((size_t)co * CIN + cin) * 9 + tap];
  bp[idx] = f2bf(v);
}

// ---------------------------------------------------------------------------
// Implicit-GEMM 3x3 conv via bf16 MFMA. Packed bf16 NHWC input [H][W][CINP],
// packed bf16 NHWC output [H][W][NT*16] (bias+relu, direct short stores —
// no LDS transpose, no epilogue barriers). K-loop fully unrolled so
// tap/ky/kx/cinl are compile-time (kills runtime div-by-24/div-by-3).
// EDGE19: staging overwrites channel 19 with bf16(edg[pixel]).
// ---------------------------------------------------------------------------
template <int CINP, int KS, int NT, bool EDGE19>
__global__ __launch_bounds__(256) void conv3x3_mfma(
    const unsigned short* __restrict__ inp, const float* __restrict__ edg,
    const unsigned short* __restrict__ bpack, const float* __restrict__ bias,
    unsigned short* __restrict__ outp) {
  constexpr int COUT = NT * 16;
  constexpr int CS = (CINP == 16) ? 24 : 40;  // LDS cin stride (16B mult)
  __shared__ __align__(16) unsigned short tile[18 * 34 * CS];

  const int tid = threadIdx.x;
  const int w0 = blockIdx.x * 32, h0 = blockIdx.y * 16, b = blockIdx.z;

  // ---- stage halo'd tile: packed pixel copy (dwordx4), zero for OOB ----
  for (int idx = tid; idx < 18 * 34; idx += 256) {
    const int r = idx / 34, c = idx - r * 34;
    const int gh = h0 + r - 1, gw = w0 + c - 1;
    unsigned short* dst = tile + (size_t)(r * 34 + c) * CS;
    if ((unsigned)gh < (unsigned)H && (unsigned)gw < (unsigned)W) {
      const unsigned short* src = inp + ((size_t)(b * H + gh) * W + gw) * CINP;
#pragma unroll
      for (int u = 0; u < CINP / 8; ++u)
        *(uint4v*)(dst + u * 8) = *(const uint4v*)(src + u * 8);
      if (EDGE19) dst[19] = f2bf(edg[(size_t)b * HW + gh * W + gw]);
    } else {
#pragma unroll
      for (int u = 0; u < CINP / 8; ++u)
        *(uint4v*)(dst + u * 8) = uint4v{0, 0, 0, 0};
    }
  }
  __syncthreads();

  // ---- K-loop (fully unrolled) ----
  const int wv = tid >> 6, lane = tid & 63;
  const int q = lane >> 4, l15 = lane & 15;
  const int rb = wv * 4;

  floatx4 acc[8][NT];
#pragma unroll
  for (int mf = 0; mf < 8; ++mf)
#pragma unroll
    for (int nt = 0; nt < NT; ++nt) acc[mf][nt] = floatx4{0.f, 0.f, 0.f, 0.f};

#pragma unroll
  for (int ks = 0; ks < KS; ++ks) {
    short8 bfrag[NT];
#pragma unroll
    for (int nt = 0; nt < NT; ++nt)
      bfrag[nt] = *(const short8*)(bpack + (size_t)(((nt * KS) + ks) * 64 + lane) * 8);

    const int kbase = ks * 32;  // compile-time
    constexpr int dummy = 0;
    int tap = (kbase) / CINP;   // folds at compile time (ks unrolled)
    const int cin_c = kbase % CINP;
    (void)dummy;
    // per-quad k offset: kq = kbase + q*8 -> tap/cin depend on q (runtime but
    // cheap: q in [0,4), only crosses a tap boundary at known points)
    const int kq = kbase + q * 8;
    int tapq = kq / CINP;
    const int cinq = kq % CINP;
    if (tapq > 8) tapq = 8;  // zero-weight pad region
    const int ky = tapq / 3, kx = tapq - ky * 3;
    const unsigned short* aptr =
        tile + (size_t)((rb + ky) * 34 + (l15 + kx)) * CS + cinq;
    (void)tap; (void)cin_c;

#pragma unroll
    for (int mf = 0; mf < 8; ++mf) {
      constexpr int mfs[8][2] = {{0,0},{0,16},{1,0},{1,16},{2,0},{2,16},{3,0},{3,16}};
      const int off = (mfs[mf][0] * 34 + mfs[mf][1]) * CS;
      const short8 af = *(const short8*)(aptr + off);
#pragma unroll
      for (int nt = 0; nt < NT; ++nt)
        acc[mf][nt] = __builtin_amdgcn_mfma_f32_16x16x32_bf16(
            af, bfrag[nt], acc[mf][nt], 0, 0, 0);
    }
  }

  // ---- epilogue: direct bf16 short stores from C-layout registers ----
  // D layout: n (=co within tile) = l15, m (=pixel col) = q*4 + rg.
#pragma unroll
  for (int nt = 0; nt < NT; ++nt) {
    const float bv = bias[nt * 16 + l15];
#pragma unroll
    for (int mf = 0; mf < 8; ++mf) {
      const int row = mf >> 1, colb = (mf & 1) * 16 + q * 4;
      unsigned short* dst =
          outp + ((size_t)(b * H + h0 + rb + row) * W + w0) * COUT + nt * 16 + l15;
#pragma unroll
      for (int rg = 0; rg < 4; ++rg) {
        const float v = fmaxf(acc[mf][nt][rg] + bv, 0.f);
        dst[(size_t)(colb + rg) * COUT] = f2bf(v);
      }
    }
  }
}

// ---------------------------------------------------------------------------
// 1x1 conv 16->19 on packed bf16 NHWC; writes packed [H][W][24] (ch19..23=0).
// 2 pixels per thread.
// ---------------------------------------------------------------------------
__global__ __launch_bounds__(256) void intra1x1_kernel(
    const unsigned short* __restrict__ f2p, const float* __restrict__ w,
    const float* __restrict__ bias, unsigned short* __restrict__ intp) {
  const int t = blockIdx.x * 256 + threadIdx.x;  // [0, B*HW/2)
  const size_t p0 = (size_t)t * 2;
  float xi[2][16];
#pragma unroll
  for (int k = 0; k < 2; ++k) {
    const unsigned short* src = f2p + (p0 + k) * 16;
    const uint4v r0 = *(const uint4v*)src;
    const uint4v r1 = *(const uint4v*)(src + 8);
    unpk2(r0.x, xi[k][0], xi[k][1]);  unpk2(r0.y, xi[k][2], xi[k][3]);
    unpk2(r0.z, xi[k][4], xi[k][5]);  unpk2(r0.w, xi[k][6], xi[k][7]);
    unpk2(r1.x, xi[k][8], xi[k][9]);  unpk2(r1.y, xi[k][10], xi[k][11]);
    unpk2(r1.z, xi[k][12], xi[k][13]); unpk2(r1.w, xi[k][14], xi[k][15]);
  }
#pragma unroll
  for (int k = 0; k < 2; ++k) {
    float a[19];
#pragma unroll
    for (int co = 0; co < 19; ++co) a[co] = bias[co];
#pragma unroll
    for (int c = 0; c < 16; ++c) {
      const float v = xi[k][c];
#pragma unroll
      for (int co = 0; co < 19; ++co) a[co] = fmaf(v, w[co * 16 + c], a[co]);
    }
    unsigned int pk[12];
#pragma unroll
    for (int j = 0; j < 9; ++j)
      pk[j] = (unsigned)f2bf(a[2 * j]) | ((unsigned)f2bf(a[2 * j + 1]) << 16);
    pk[9] = (unsigned)f2bf(a[18]);
    pk[10] = 0; pk[11] = 0;
    unsigned short* dst = intp + (p0 + k) * 24;
#pragma unroll
    for (int u = 0; u < 3; ++u)
      *(uint4v*)(dst + u * 8) = uint4v{pk[u * 4], pk[u * 4 + 1], pk[u * 4 + 2], pk[u * 4 + 3]};
  }
}

// ---------------------------------------------------------------------------
// 1x1 conv 32->11 + sigmoid + normalize on packed bf16 NHWC; writes fp32
// planes [B][11][HW]. 1 pixel per thread.
// ---------------------------------------------------------------------------
__global__ __launch_bounds__(256) void guide3_kernel(
    const unsigned short* __restrict__ g2p, const float* __restrict__ w,
    const float* __restrict__ bias, float* __restrict__ gf) {
  const int t = blockIdx.x * 256 + threadIdx.x;  // [0, B*HW)
  const int b = t >> 18;                          // HW = 2^18
  const int s = t & (HW - 1);
  const unsigned short* src = g2p + (size_t)t * 32;
  float xi[32];
#pragma unroll
  for (int u = 0; u < 4; ++u) {
    const uint4v r = *(const uint4v*)(src + u * 8);
    unpk2(r.x, xi[u * 8 + 0], xi[u * 8 + 1]);
    unpk2(r.y, xi[u * 8 + 2], xi[u * 8 + 3]);
    unpk2(r.z, xi[u * 8 + 4], xi[u * 8 + 5]);
    unpk2(r.w, xi[u * 8 + 6], xi[u * 8 + 7]);
  }
  float g[11], sum = 0.f;
#pragma unroll
  for (int co = 0; co < 11; ++co) {
    float a = bias[co];
#pragma unroll
    for (int c = 0; c < 32; ++c) a = fmaf(xi[c], w[co * 32 + c], a);
    g[co] = 1.f / (1.f + expf(-a));
    sum += g[co];
  }
  const float inv = 1.f / (sum + 1e-9f);
#pragma unroll
  for (int co = 0; co < 11; ++co)
    gf[(size_t)(b * 11 + co) * HW + s] = g[co] * inv;
}

// ---------------------------------------------------------------------------
// argmax over 19 channels -> float index, 4 pixels/thread
// ---------------------------------------------------------------------------
__global__ __launch_bounds__(256) void argmax_kernel(
    const float* __restrict__ x, float* __restrict__ sx) {
  const int t = blockIdx.x * 256 + threadIdx.x;
  const int b = t / (HW / 4);
  const int s4 = (t - b * (HW / 4)) * 4;
  const float* xp = x + (size_t)b * 19 * HW + s4;
  float4 bv = *(const float4*)xp;
  float ix = 0.f, iy = 0.f, iz = 0.f, iw = 0.f;
#pragma unroll
  for (int c = 1; c < 19; ++c) {
    const float4 v = *(const float4*)(xp + (size_t)c * HW);
    const float fc = (float)c;
    if (v.x > bv.x) { bv.x = v.x; ix = fc; }
    if (v.y > bv.y) { bv.y = v.y; iy = fc; }
    if (v.z > bv.z) { bv.z = v.z; iz = fc; }
    if (v.w > bv.w) { bv.w = v.w; iw = fc; }
  }
  *(float4*)(sx + (size_t)b * HW + s4) = float4{ix, iy, iz, iw};
}

__device__ inline void load_row6(const float* __restrict__ plane, int hh,
                                 int w0, float r[6]) {
#pragma unroll
  for (int i = 0; i < 6; ++i) r[i] = 0.f;
  if ((unsigned)hh < (unsigned)H) {
    const float* rp = plane + (size_t)hh * W + w0;
    const float4 m = *(const float4*)rp;
    r[1] = m.x; r[2] = m.y; r[3] = m.z; r[4] = m.w;
    if (w0 > 0) r[0] = rp[-1];
    if (w0 + 4 < W) r[5] = rp[4];
  }
}

__global__ __launch_bounds__(256) void edge_kernel(
    const float* __restrict__ sx, float* __restrict__ edge) {
  const int t = blockIdx.x * 256 + threadIdx.x;
  const int b = t / (HW / 4);
  const int s4 = (t - b * (HW / 4)) * 4;
  const int h = s4 / W, w0 = s4 - h * W;
  const float* sp = sx + (size_t)b * HW;
  float r0[6], r1[6], r2[6];
  load_row6(sp, h - 1, w0, r0);
  load_row6(sp, h, w0, r1);
  load_row6(sp, h + 1, w0, r2);
  float o[4];
#pragma unroll
  for (int k = 0; k < 4; ++k)
    o[k] = r0[k] + r0[k + 1] + r0[k + 2] + r1[k] + r1[k + 2] + r2[k] +
           r2[k + 1] + r2[k + 2] - 8.f * r1[k + 1];
  *(float4*)(edge + (size_t)b * HW + s4) = float4{o[0], o[1], o[2], o[3]};
}

// ---------------------------------------------------------------------------
// combine, 4 pixels/thread; intra read from packed bf16 [H][W][24].
// ---------------------------------------------------------------------------
__global__ __launch_bounds__(256) void combine_kernel(
    const float* __restrict__ x, const unsigned short* __restrict__ intp,
    const float* __restrict__ gf, float* __restrict__ out) {
  const int t = blockIdx.x * 256 + threadIdx.x;
  const int b = t / (HW / 4);
  const int s4 = (t - b * (HW / 4)) * 4;
  const int h = s4 / W, w0 = s4 - h * W;
  const float* gp = gf + (size_t)b * 11 * HW + s4;

  float g[11][4];
#pragma unroll
  for (int m = 0; m < 11; ++m) {
    if (m == 9) continue;  // all-zero shift channel
    const float4 v = *(const float4*)(gp + (size_t)m * HW);
    g[m][0] = v.x; g[m][1] = v.y; g[m][2] = v.z; g[m][3] = v.w;
  }

  const unsigned short* ip = intp + ((size_t)b * HW + s4) * 24;
  for (int c = 0; c < 19; ++c) {
    const float* xc = x + (size_t)(b * 19 + c) * HW;
    float r0[6], r1[6], r2[6];
    load_row6(xc, h - 1, w0, r0);
    load_row6(xc, h, w0, r1);
    load_row6(xc, h + 1, w0, r2);
    float o[4];
#pragma unroll
    for (int k = 0; k < 4; ++k) {
      const float itv = bf2f(ip[(size_t)k * 24 + c]);
      float a = g[0][k] * r1[k + 1];
      a = fmaf(g[1][k], r0[k], a);
      a = fmaf(g[2][k], r0[k + 1], a);
      a = fmaf(g[3][k], r0[k + 2], a);
      a = fmaf(g[4][k], r1[k], a);
      a = fmaf(g[5][k], r1[k + 2], a);
      a = fmaf(g[6][k], r2[k], a);
      a = fmaf(g[7][k], r2[k + 1], a);
      a = fmaf(g[8][k], r2[k + 2], a);
      a = fmaf(g[10][k], itv, a);
      o[k] = a;
    }
    *(float4*)(out + (size_t)(b * 19 + c) * HW + s4) =
        float4{o[0], o[1], o[2], o[3]};
  }
}

// ---------------------------------------------------------------------------
extern "C" void kernel_launch(void* const* d_in, const int* in_sizes, int n_in,
                              void* d_out, int out_size, void* d_ws,
                              size_t ws_size, hipStream_t stream) {
  const float* x     = (const float*)d_in[0];
  const float* image = (const float*)d_in[1];
  const float* iw1 = (const float*)d_in[2];
  const float* ib1 = (const float*)d_in[3];
  const float* iw2 = (const float*)d_in[4];
  const float* ib2 = (const float*)d_in[5];
  const float* iw3 = (const float*)d_in[6];
  const float* ib3 = (const float*)d_in[7];
  const float* gw1 = (const float*)d_in[8];
  const float* gb1 = (const float*)d_in[9];
  const float* gw2 = (const float*)d_in[10];
  const float* gb2 = (const float*)d_in[11];
  const float* gw3 = (const float*)d_in[12];
  const float* gb3 = (const float*)d_in[13];

  // Workspace layout in FLOAT units (1 float = 2 bf16):
  //   sx   [  0,   2)*HW   argmax map
  //   f1p  [  2,  18)*HW   [B][H][W][16] bf16
  //   f2p  [ 18,  34)*HW   [B][H][W][16] bf16
  //   intp [ 34,  58)*HW   [B][H][W][24] bf16
  //   g1p  [ 58,  90)*HW   [B][H][W][32] bf16
  //   g2p  [ 90, 122)*HW   [B][H][W][32] bf16
  //   bpacks at 122*HW
  float* ws = (float*)d_ws;
  float* sx = ws;
  unsigned short* f1p  = (unsigned short*)(ws + (size_t)2 * HW);
  unsigned short* f2p  = (unsigned short*)(ws + (size_t)18 * HW);
  unsigned short* intp = (unsigned short*)(ws + (size_t)34 * HW);
  unsigned short* g1p  = (unsigned short*)(ws + (size_t)58 * HW);
  unsigned short* g2p  = (unsigned short*)(ws + (size_t)90 * HW);
  unsigned short* bp_ic2 = (unsigned short*)(ws + (size_t)122 * HW);  // 2560
  unsigned short* bp_gc1 = bp_ic2 + 4096;                             // 7168
  unsigned short* bp_gc2 = bp_gc1 + 12288;                            // 9216

  float* out0 = (float*)d_out;               // (2,19,512,512)
  float* gfo  = out0 + (size_t)2 * 19 * HW;  // (2,11,1,512,512)
  float* edg  = gfo + (size_t)2 * 11 * HW;   // (2,1,512,512)

  const dim3 blk16(16, 16);
  const dim3 grd16(W / 16, H / 16, B);
  const dim3 grdM(W / 32, H / 16, B);
  const int flat4 = (B * HW / 4) / 256;  // 512

  argmax_kernel<<<flat4, 256, 0, stream>>>(x, sx);
  edge_kernel<<<flat4, 256, 0, stream>>>(sx, edg);

  repack_w<16, 16, 16, 5><<<10, 256, 0, stream>>>(iw2, bp_ic2);
  repack_w<20, 24, 32, 7><<<28, 256, 0, stream>>>(gw1, bp_gc1);
  repack_w<32, 32, 32, 9><<<36, 256, 0, stream>>>(gw2, bp_gc2);

  conv3x3_fp32_pack<3, 16, true><<<grd16, blk16, 0, stream>>>(image, iw1, ib1, f1p);
  // intra conv2 (16->16) -> f2p
  conv3x3_mfma<16, 5, 1, false><<<grdM, 256, 0, stream>>>(f1p, nullptr, bp_ic2, ib2, f2p);
  // intra 1x1 16->19 -> packed intra [H][W][24]
  intra1x1_kernel<<<(B * HW / 2) / 256, 256, 0, stream>>>(f2p, iw3, ib3, intp);
  // guide conv1 (20->32, edge in ch19) -> g1p
  conv3x3_mfma<24, 7, 2, true><<<grdM, 256, 0, stream>>>(intp, edg, bp_gc1, gb1, g1p);
  // guide conv2 (32->32) -> g2p
  conv3x3_mfma<32, 9, 2, false><<<grdM, 256, 0, stream>>>(g1p, nullptr, bp_gc2, gb2, g2p);
  // guide 1x1 32->11 + sigmoid + normalize -> gfo
  guide3_kernel<<<(B * HW) / 256, 256, 0, stream>>>(g2p, gw3, gb3, gfo);

  combine_kernel<<<flat4, 256, 0, stream>>>(x, intp, gfo, out0);
}